// Round 13
// baseline (3843.470 us; speedup 1.0000x reference)
//
#include <hip/hip_runtime.h>
#include <cstdint>
#include <cstddef>

typedef _Float16 f16;
typedef _Float16 f16x4 __attribute__((ext_vector_type(4)));
typedef _Float16 f16x8 __attribute__((ext_vector_type(8)));
typedef float f32x4 __attribute__((ext_vector_type(4)));

#define MFMA16(a, b, c) __builtin_amdgcn_mfma_f32_16x16x16f16((a), (b), (c), 0, 0, 0)
#define MFMA32(a, b, c) __builtin_amdgcn_mfma_f32_16x16x32_f16((a), (b), (c), 0, 0, 0)

constexpr int TT = 1024, DIN = 128, DH = 512, DOUT = 128;
constexpr size_t O_ELEMS = (size_t)64 * 1024 * 128;

// Row swizzle for [row][1KB] LDS tiles (R8..R12-proven).
__device__ __forceinline__ uint32_t SW(uint32_t r) {
    return ((r & 7u) << 4) ^ ((r & 8u) << 2);
}

// ---------------- Pass 1: xI = X(65536x128) @ wI(128x512) -> H region (fp32) ----------------
__global__ __launch_bounds__(256, 1) void k_xI(const float* __restrict__ X,
                                               const float* __restrict__ wI,
                                               float* __restrict__ xI) {
    __shared__ __align__(16) f16 Bt[DH][136];
    __shared__ __align__(16) f16 At[64][136];
    const int tid = threadIdx.x;
    const int wv = tid >> 6, ln = tid & 63, l15 = ln & 15, g = ln >> 4;
    const int m0 = (int)blockIdx.x * 64;

    // stage B (transpose to [n][k]) in 4x4 register blocks (b64 writes)
    #pragma unroll
    for (int u = 0; u < 16; ++u) {
        const int uid = u * 256 + tid;      // 0..4095
        const int c4 = (uid & 127) << 2;    // n base 0..508
        const int r4 = (uid >> 7) << 2;     // k base 0..124
        float4 w[4];
        #pragma unroll
        for (int j = 0; j < 4; ++j)
            w[j] = *(const float4*)(wI + (size_t)(r4 + j) * DH + c4);
        #pragma unroll
        for (int n = 0; n < 4; ++n) {
            f16x4 v;
            #pragma unroll
            for (int j = 0; j < 4; ++j) v[j] = (f16)((&w[j].x)[n]);
            *(f16x4*)(&Bt[c4 + n][r4]) = v;
        }
    }
    {
        int r = tid >> 2;
        int cb = (tid & 3) << 5;
        #pragma unroll
        for (int u = 0; u < 8; ++u) {
            int c = cb + u * 4;
            const float4 x4 = *(const float4*)(X + (size_t)(m0 + r) * DIN + c);
            f16x4 h4;
            h4[0] = (f16)x4.x; h4[1] = (f16)x4.y; h4[2] = (f16)x4.z; h4[3] = (f16)x4.w;
            *(f16x4*)((char*)&At[r][0] + c * 2) = h4;
        }
    }
    __syncthreads();

    f32x4 acc[4][8];
    #pragma unroll
    for (int mt = 0; mt < 4; ++mt)
        #pragma unroll
        for (int nt = 0; nt < 8; ++nt) acc[mt][nt] = (f32x4){0.f, 0.f, 0.f, 0.f};

    #pragma unroll
    for (int c = 0; c < 8; ++c) {
        const int k0 = c * 16 + g * 4;
        f16x4 a[4];
        #pragma unroll
        for (int mt = 0; mt < 4; ++mt)
            a[mt] = *(const f16x4*)((const char*)&At[mt * 16 + l15][0] + k0 * 2);
        #pragma unroll
        for (int nt = 0; nt < 8; ++nt) {
            const int n = wv * 128 + nt * 16 + l15;
            const f16x4 b = *(const f16x4*)((const char*)&Bt[n][0] + k0 * 2);
            #pragma unroll
            for (int mt = 0; mt < 4; ++mt) acc[mt][nt] = MFMA16(a[mt], b, acc[mt][nt]);
        }
    }
    #pragma unroll
    for (int mt = 0; mt < 4; ++mt) {
        #pragma unroll
        for (int i = 0; i < 4; ++i) {
            const int m = m0 + mt * 16 + g * 4 + i;
            float* orow = xI + (size_t)m * DH + wv * 128 + l15;
            #pragma unroll
            for (int nt = 0; nt < 8; ++nt) orow[nt * 16] = acc[mt][nt][i];
        }
    }
}

// ---------------- Pass 2: recurrent scan -------------------------------------------------
// R12 base (proven 2.04 ms) + rotated chunk order & cross-barrier ring priming:
//  * wave wv processes k-chunks kc = (2wv + c) & 15; Brf staged pre-rotated so the
//    register array keeps compile-time indices.
//  * chunks 2wv, 2wv+1 are the j-slice this wave itself writes -> next step's first
//    two A-frags are read BEFORE the barrier (own data, ordered by the lgkmcnt(0)
//    write drain). B-tile reads are static weights: always safe to pre-issue.
//    Post-barrier only 1 dependent read remains before the first MFMA (was 6).
//  * waves start their hb sweep at 8 different offsets (de-bunched LDS pressure).
// LDS map: [0,16K) hb[0] | [16K,32K) hb[1] | [32K,160K) 8 B j-tiles.
__global__ __launch_bounds__(512, 2) void k_scan(const float* __restrict__ wR,
                                                 const float* __restrict__ h0,
                                                 float* __restrict__ Hb) {
    __shared__ __align__(16) char sm[163840];
    const int tid = threadIdx.x;
    const int wv = tid >> 6, ln = tid & 63, l15 = ln & 15, g = ln >> 4;
    const int bb = (int)blockIdx.x * 16;

    // ---- stage wR: 3 register j-tiles, PRE-ROTATED: Brf[q][c] holds k-chunk (2wv+c)&15 ----
    f16x8 Brf[3][16];
    #pragma unroll
    for (int q = 0; q < 3; ++q) {
        const int j = wv * 64 + q * 16 + l15;
        #pragma unroll
        for (int c = 0; c < 16; ++c) {
            const int kc = (2 * wv + c) & 15;
            const float* pw = wR + (size_t)(kc * 32 + g * 8) * DH + j;
            f16x8 v;
            #pragma unroll
            for (int i = 0; i < 8; ++i) v[i] = (f16)pw[(size_t)i * DH];
            Brf[q][c] = v;
        }
    }
    // ---- stage wR: 1 LDS j-tile per wave (j = t8*64 + 48 + j16), cooperative ----
    for (int idx = tid; idx < 8 * 16 * 512; idx += 512) {
        const int j16 = idx & 15;
        const int k = (idx >> 4) & 511;
        const int t8 = idx >> 13;
        const float v = wR[(size_t)k * DH + t8 * 64 + 48 + j16];
        *(f16*)(sm + 32768 + t8 * 16384 + j16 * 1024 +
                (((uint32_t)(k * 2)) ^ SW((uint32_t)j16))) = (f16)v;
    }
    // ---- h0 broadcast into hb[0] ----
    {
        const int j = tid;  // 0..511
        const f16 v = (f16)h0[j];
        #pragma unroll
        for (uint32_t r = 0; r < 16; ++r)
            *(f16*)(sm + r * 1024 + (((uint32_t)(j * 2)) ^ SW(r))) = v;
    }

    // this thread's batch row and j-base
    float* Hp = Hb + (size_t)(bb + l15) * TT * DH + wv * 64 + g * 4;

    // rotated k-chunk read offset: off = ((((wv<<7) + (c<<6)) & 960) ^ pre)
    const uint32_t rb = ((uint32_t)wv) << 7;  // (2wv)<<6
    const uint32_t pre =
        (((uint32_t)(g ^ (l15 & 7))) << 4) ^ (((uint32_t)(l15 & 8)) << 2);
    const uint32_t lanebase = (uint32_t)l15 * 1024;
    const uint32_t wbase = (uint32_t)(wv * 128 + g * 8);  // j*2 base for hb writes
    const uint32_t swl = SW((uint32_t)l15);

    // prologue: xI(0) into xr (vector loads)
    f32x4 xr[4];
    #pragma unroll
    for (int q = 0; q < 4; ++q) xr[q] = *(const f32x4*)(Hp + q * 16);

    f32x4 acc[4];
    f16x8 ab[3], b3[3];  // ring; persists across the barrier

    __syncthreads();

    // prologue prime (t=0, hb[0]): A chunks 0,1 (rotated) + B chunks 0,1,2
    {
        const char* hbp = sm + lanebase;
        const char* blp = sm + 32768 + (uint32_t)wv * 16384 + lanebase;
        const uint32_t o0 = ((rb + 0u) & 960u) ^ pre;
        const uint32_t o1 = ((rb + 64u) & 960u) ^ pre;
        const uint32_t o2 = ((rb + 128u) & 960u) ^ pre;
        ab[0] = *(const f16x8*)(hbp + o0);
        ab[1] = *(const f16x8*)(hbp + o1);
        b3[0] = *(const f16x8*)(blp + o0);
        b3[1] = *(const f16x8*)(blp + o1);
        b3[2] = *(const f16x8*)(blp + o2);
    }

    #pragma unroll 1
    for (int t = 0; t < TT; ++t) {
        const uint32_t p = (uint32_t)(t & 1);
        const char* hbp = sm + p * 16384 + lanebase;
        const char* blp = sm + 32768 + (uint32_t)wv * 16384 + lanebase;

        // post-barrier: the only dependent read before MFMAs — A chunk 2
        ab[2] = *(const f16x8*)(hbp + (((rb + 128u) & 960u) ^ pre));

        // acc <- xI(t)  (MFMA C-in carries the input projection)
        #pragma unroll
        for (int q = 0; q < 4; ++q) acc[q] = xr[q];
        // prefetch xI(t+1); loads stay in flight across the counted barrier
        if (t + 1 < TT) {
            #pragma unroll
            for (int q = 0; q < 4; ++q) xr[q] = *(const f32x4*)(Hp + 512 + q * 16);
        }

        // wR^T @ h^T : 16 rotated K=32 chunks; 3-deep static ring on both streams
        #pragma unroll
        for (int c = 0; c < 16; ++c) {
            const int s = c % 3;  // static after full unroll
            const f16x8 a = ab[s];
            const f16x8 bt = b3[s];
            if (c < 13) {
                const uint32_t off3 = ((rb + (uint32_t)((c + 3) << 6)) & 960u) ^ pre;
                ab[s] = *(const f16x8*)(hbp + off3);
                b3[s] = *(const f16x8*)(blp + off3);
            }
            acc[0] = MFMA32(Brf[0][c], a, acc[0]);
            acc[1] = MFMA32(Brf[1][c], a, acc[1]);
            acc[2] = MFMA32(Brf[2][c], a, acc[2]);
            acc[3] = MFMA32(bt, a, acc[3]);
        }

        // epilogue: th = tanh(acc); H(t) <- float4 th; hb[p^1] <- packed f16x4
        {
            char* hw = sm + (p ^ 1u) * 16384 + lanebase;
            #pragma unroll
            for (int q = 0; q < 4; ++q) {
                f32x4 th4;
                f16x4 hv;
                #pragma unroll
                for (int i = 0; i < 4; ++i) {
                    const float x = acc[q][i];
                    const float e = __builtin_amdgcn_exp2f(x * 2.8853900817779268f);
                    const float th = 1.0f - 2.0f * __builtin_amdgcn_rcpf(e + 1.0f);
                    th4[i] = th;
                    hv[i] = (f16)th;
                }
                *(f32x4*)(Hp + q * 16) = th4;  // H(t), coalesced dwordx4
                *(f16x4*)(hw + ((wbase + (uint32_t)q * 32) ^ swl)) = hv;  // b64 write
            }
        }
        // drain hb writes (LDS only; globals keep flying)
        asm volatile("s_waitcnt lgkmcnt(0)" ::: "memory");
        // cross-barrier prime for step t+1: A chunks 0,1 = THIS wave's own just-written
        // j-slice (safe pre-barrier); B chunks 0,1,2 are static weights (always safe).
        {
            const char* hbn = sm + (p ^ 1u) * 16384 + lanebase;
            const uint32_t o0 = ((rb + 0u) & 960u) ^ pre;
            const uint32_t o1 = ((rb + 64u) & 960u) ^ pre;
            const uint32_t o2 = ((rb + 128u) & 960u) ^ pre;
            ab[0] = *(const f16x8*)(hbn + o0);
            ab[1] = *(const f16x8*)(hbn + o1);
            b3[0] = *(const f16x8*)(blp + o0);
            b3[1] = *(const f16x8*)(blp + o1);
            b3[2] = *(const f16x8*)(blp + o2);
        }
        asm volatile("s_barrier" ::: "memory");

        Hp += DH;
    }
}

// ---------------- Pass 3: O = H(65536x512) @ wO(512x128) ----------------
__global__ __launch_bounds__(256, 1) void k_O(const float* __restrict__ H,
                                              const float* __restrict__ wO,
                                              float* __restrict__ O) {
    __shared__ __align__(16) f16 Bt[DOUT][520];
    __shared__ __align__(16) f16 At[64][136];
    const int tid = threadIdx.x;
    const int wv = tid >> 6, ln = tid & 63, l15 = ln & 15, g = ln >> 4;
    const int m0 = (int)blockIdx.x * 64;

    // stage B (transpose to [n][k]) in 4x4 register blocks (b64 writes)
    #pragma unroll
    for (int u = 0; u < 16; ++u) {
        const int uid = u * 256 + tid;     // 0..4095
        const int c4 = (uid & 31) << 2;    // n base 0..124
        const int r4 = (uid >> 5) << 2;    // k base 0..508
        float4 w[4];
        #pragma unroll
        for (int j = 0; j < 4; ++j)
            w[j] = *(const float4*)(wO + (size_t)(r4 + j) * DOUT + c4);
        #pragma unroll
        for (int n = 0; n < 4; ++n) {
            f16x4 v;
            #pragma unroll
            for (int j = 0; j < 4; ++j) v[j] = (f16)((&w[j].x)[n]);
            *(f16x4*)(&Bt[c4 + n][r4]) = v;
        }
    }

    f32x4 acc[8];
    #pragma unroll
    for (int nt = 0; nt < 8; ++nt) acc[nt] = (f32x4){0.f, 0.f, 0.f, 0.f};

    for (int kc = 0; kc < 4; ++kc) {
        __syncthreads();
        {
            int r = tid >> 2;
            int cb = (tid & 3) << 5;
            #pragma unroll
            for (int u = 0; u < 8; ++u) {
                int c = cb + u * 4;
                const float4 x4 = *(const float4*)(H + (size_t)(m0 + r) * DH + kc * 128 + c);
                f16x4 h4;
                h4[0] = (f16)x4.x; h4[1] = (f16)x4.y; h4[2] = (f16)x4.z; h4[3] = (f16)x4.w;
                *(f16x4*)((char*)&At[r][0] + c * 2) = h4;
            }
        }
        __syncthreads();
        #pragma unroll
        for (int c = 0; c < 8; ++c) {
            const int k0 = c * 16 + g * 4;
            const f16x4 a = *(const f16x4*)((const char*)&At[wv * 16 + l15][0] + k0 * 2);
            #pragma unroll
            for (int nt = 0; nt < 8; ++nt) {
                const f16x4 b =
                    *(const f16x4*)((const char*)&Bt[nt * 16 + l15][0] + (kc * 128 + k0) * 2);
                acc[nt] = MFMA16(a, b, acc[nt]);
            }
        }
    }
    #pragma unroll
    for (int i = 0; i < 4; ++i) {
        const int m = m0 + wv * 16 + g * 4 + i;
        #pragma unroll
        for (int nt = 0; nt < 8; ++nt) O[(size_t)m * DOUT + nt * 16 + l15] = acc[nt][i];
    }
}

extern "C" void kernel_launch(void* const* d_in, const int* in_sizes, int n_in,
                              void* d_out, int out_size, void* d_ws, size_t ws_size,
                              hipStream_t stream) {
    const float* X  = (const float*)d_in[0];
    const float* h0 = (const float*)d_in[1];
    const float* wI = (const float*)d_in[2];
    const float* wR = (const float*)d_in[3];
    const float* wO = (const float*)d_in[4];
    float* O = (float*)d_out;
    float* H = O + O_ELEMS;  // H region; also holds xI (fp32) before in-place scan

    k_xI<<<1024, 256, 0, stream>>>(X, wI, H);   // xI -> H region
    k_scan<<<4, 512, 0, stream>>>(wR, h0, H);   // in-place: xI -> H
    k_O<<<1024, 256, 0, stream>>>(H, wO, O);    // O = H @ wO
}

// Round 14
// 2103.492 us; speedup vs baseline: 1.8272x; 1.8272x over previous
//
#include <hip/hip_runtime.h>
#include <cstdint>
#include <cstddef>

typedef _Float16 f16;
typedef _Float16 f16x4 __attribute__((ext_vector_type(4)));
typedef _Float16 f16x8 __attribute__((ext_vector_type(8)));
typedef float f32x4 __attribute__((ext_vector_type(4)));

#define MFMA16(a, b, c) __builtin_amdgcn_mfma_f32_16x16x16f16((a), (b), (c), 0, 0, 0)
#define MFMA32(a, b, c) __builtin_amdgcn_mfma_f32_16x16x32_f16((a), (b), (c), 0, 0, 0)

constexpr int TT = 1024, DIN = 128, DH = 512, DOUT = 128;
constexpr size_t O_ELEMS = (size_t)64 * 1024 * 128;

// Row swizzle for [row][1KB] LDS tiles (R8..R12-proven).
__device__ __forceinline__ uint32_t SW(uint32_t r) {
    return ((r & 7u) << 4) ^ ((r & 8u) << 2);
}

// ---------------- Pass 1: xI = X(65536x128) @ wI(128x512) -> H region (fp32) ----------------
__global__ __launch_bounds__(256, 1) void k_xI(const float* __restrict__ X,
                                               const float* __restrict__ wI,
                                               float* __restrict__ xI) {
    __shared__ __align__(16) f16 Bt[DH][136];
    __shared__ __align__(16) f16 At[64][136];
    const int tid = threadIdx.x;
    const int wv = tid >> 6, ln = tid & 63, l15 = ln & 15, g = ln >> 4;
    const int m0 = (int)blockIdx.x * 64;

    // stage B (transpose to [n][k]) in 4x4 register blocks (b64 writes)
    #pragma unroll
    for (int u = 0; u < 16; ++u) {
        const int uid = u * 256 + tid;      // 0..4095
        const int c4 = (uid & 127) << 2;    // n base 0..508
        const int r4 = (uid >> 7) << 2;     // k base 0..124
        float4 w[4];
        #pragma unroll
        for (int j = 0; j < 4; ++j)
            w[j] = *(const float4*)(wI + (size_t)(r4 + j) * DH + c4);
        #pragma unroll
        for (int n = 0; n < 4; ++n) {
            f16x4 v;
            #pragma unroll
            for (int j = 0; j < 4; ++j) v[j] = (f16)((&w[j].x)[n]);
            *(f16x4*)(&Bt[c4 + n][r4]) = v;
        }
    }
    {
        int r = tid >> 2;
        int cb = (tid & 3) << 5;
        #pragma unroll
        for (int u = 0; u < 8; ++u) {
            int c = cb + u * 4;
            const float4 x4 = *(const float4*)(X + (size_t)(m0 + r) * DIN + c);
            f16x4 h4;
            h4[0] = (f16)x4.x; h4[1] = (f16)x4.y; h4[2] = (f16)x4.z; h4[3] = (f16)x4.w;
            *(f16x4*)((char*)&At[r][0] + c * 2) = h4;
        }
    }
    __syncthreads();

    f32x4 acc[4][8];
    #pragma unroll
    for (int mt = 0; mt < 4; ++mt)
        #pragma unroll
        for (int nt = 0; nt < 8; ++nt) acc[mt][nt] = (f32x4){0.f, 0.f, 0.f, 0.f};

    #pragma unroll
    for (int c = 0; c < 8; ++c) {
        const int k0 = c * 16 + g * 4;
        f16x4 a[4];
        #pragma unroll
        for (int mt = 0; mt < 4; ++mt)
            a[mt] = *(const f16x4*)((const char*)&At[mt * 16 + l15][0] + k0 * 2);
        #pragma unroll
        for (int nt = 0; nt < 8; ++nt) {
            const int n = wv * 128 + nt * 16 + l15;
            const f16x4 b = *(const f16x4*)((const char*)&Bt[n][0] + k0 * 2);
            #pragma unroll
            for (int mt = 0; mt < 4; ++mt) acc[mt][nt] = MFMA16(a[mt], b, acc[mt][nt]);
        }
    }
    #pragma unroll
    for (int mt = 0; mt < 4; ++mt) {
        #pragma unroll
        for (int i = 0; i < 4; ++i) {
            const int m = m0 + mt * 16 + g * 4 + i;
            float* orow = xI + (size_t)m * DH + wv * 128 + l15;
            #pragma unroll
            for (int nt = 0; nt < 8; ++nt) orow[nt * 16] = acc[mt][nt][i];
        }
    }
}

// ---------------- Pass 2: recurrent scan (R12, byte-identical — proven 2.04 ms) ----------
// 4 blocks x 16 batches, 8 waves/block (2/SIMD). Transposed x32 MFMA:
// D = wR^T (A: Brf regs / LDS tile) * h^T (B: hb). Thread (l15,g) owns batch l15,
// j = wv*64 + q*16 + g*4 + i -> contiguous-in-j per thread.
// LDS map: [0,16K) hb[0] | [16K,32K) hb[1] | [32K,160K) 8 B j-tiles.
__global__ __launch_bounds__(512, 2) void k_scan(const float* __restrict__ wR,
                                                 const float* __restrict__ h0,
                                                 float* __restrict__ Hb) {
    __shared__ __align__(16) char sm[163840];
    const int tid = threadIdx.x;
    const int wv = tid >> 6, ln = tid & 63, l15 = ln & 15, g = ln >> 4;
    const int bb = (int)blockIdx.x * 16;

    // ---- stage wR: 3 register j-tiles per wave; frag[e] = wR[c*32+g*8+e][j] ----
    f16x8 Brf[3][16];
    #pragma unroll
    for (int q = 0; q < 3; ++q) {
        const int j = wv * 64 + q * 16 + l15;
        #pragma unroll
        for (int c = 0; c < 16; ++c) {
            const float* pw = wR + (size_t)(c * 32 + g * 8) * DH + j;
            f16x8 v;
            #pragma unroll
            for (int i = 0; i < 8; ++i) v[i] = (f16)pw[(size_t)i * DH];
            Brf[q][c] = v;
        }
    }
    // ---- stage wR: 1 LDS j-tile per wave (j = t8*64 + 48 + j16), cooperative ----
    for (int idx = tid; idx < 8 * 16 * 512; idx += 512) {
        const int j16 = idx & 15;
        const int k = (idx >> 4) & 511;
        const int t8 = idx >> 13;
        const float v = wR[(size_t)k * DH + t8 * 64 + 48 + j16];
        *(f16*)(sm + 32768 + t8 * 16384 + j16 * 1024 +
                (((uint32_t)(k * 2)) ^ SW((uint32_t)j16))) = (f16)v;
    }
    // ---- h0 broadcast into hb[0] ----
    {
        const int j = tid;  // 0..511
        const f16 v = (f16)h0[j];
        #pragma unroll
        for (uint32_t r = 0; r < 16; ++r)
            *(f16*)(sm + r * 1024 + (((uint32_t)(j * 2)) ^ SW(r))) = v;
    }

    // this thread's batch row and j-base
    float* Hp = Hb + (size_t)(bb + l15) * TT * DH + wv * 64 + g * 4;

    // k-chunk read offset: off = (c<<6) ^ pre (both LDS streams)
    const uint32_t pre =
        (((uint32_t)(g ^ (l15 & 7))) << 4) ^ (((uint32_t)(l15 & 8)) << 2);
    const uint32_t lanebase = (uint32_t)l15 * 1024;
    const uint32_t wbase = (uint32_t)(wv * 128 + g * 8);  // j*2 base for hb writes
    const uint32_t swl = SW((uint32_t)l15);

    // prologue: xI(0) into xr (vector loads)
    f32x4 xr[4];
    #pragma unroll
    for (int q = 0; q < 4; ++q) xr[q] = *(const f32x4*)(Hp + q * 16);

    f32x4 acc[4];

    __syncthreads();

    #pragma unroll 1
    for (int t = 0; t < TT; ++t) {
        const uint32_t p = (uint32_t)(t & 1);
        // acc <- xI(t)  (MFMA C-in carries the input projection)
        #pragma unroll
        for (int q = 0; q < 4; ++q) acc[q] = xr[q];
        // prefetch xI(t+1); loads stay in flight across the counted barrier
        if (t + 1 < TT) {
            #pragma unroll
            for (int q = 0; q < 4; ++q) xr[q] = *(const f32x4*)(Hp + 512 + q * 16);
        }

        // wR^T @ h^T : 16 K=32 chunks; 3-deep static ring on both LDS streams
        {
            const char* hbp = sm + p * 16384 + lanebase;
            const char* blp = sm + 32768 + (uint32_t)wv * 16384 + lanebase;
            f16x8 ab[3], b3[3];
            #pragma unroll
            for (int s = 0; s < 3; ++s) {
                const uint32_t off = (((uint32_t)s) << 6) ^ pre;
                ab[s] = *(const f16x8*)(hbp + off);
                b3[s] = *(const f16x8*)(blp + off);
            }
            #pragma unroll
            for (int c = 0; c < 16; ++c) {
                const int s = c % 3;  // static after full unroll
                const f16x8 a = ab[s];
                const f16x8 bt = b3[s];
                if (c < 13) {
                    const uint32_t off3 = (((uint32_t)(c + 3)) << 6) ^ pre;
                    ab[s] = *(const f16x8*)(hbp + off3);
                    b3[s] = *(const f16x8*)(blp + off3);
                }
                acc[0] = MFMA32(Brf[0][c], a, acc[0]);
                acc[1] = MFMA32(Brf[1][c], a, acc[1]);
                acc[2] = MFMA32(Brf[2][c], a, acc[2]);
                acc[3] = MFMA32(bt, a, acc[3]);
            }
        }

        // epilogue: th = tanh(acc); H(t) <- float4 th; hb[p^1] <- packed f16x4
        {
            char* hw = sm + (p ^ 1u) * 16384 + lanebase;
            #pragma unroll
            for (int q = 0; q < 4; ++q) {
                f32x4 th4;
                f16x4 hv;
                #pragma unroll
                for (int i = 0; i < 4; ++i) {
                    const float x = acc[q][i];
                    const float e = __builtin_amdgcn_exp2f(x * 2.8853900817779268f);
                    const float th = 1.0f - 2.0f * __builtin_amdgcn_rcpf(e + 1.0f);
                    th4[i] = th;
                    hv[i] = (f16)th;
                }
                *(f32x4*)(Hp + q * 16) = th4;  // H(t), coalesced dwordx4
                *(f16x4*)(hw + ((wbase + (uint32_t)q * 32) ^ swl)) = hv;  // b64 write
            }
        }
        // Counted barrier: LDS-only drain; global loads/stores keep flying.
        asm volatile("s_waitcnt lgkmcnt(0)\n\ts_barrier" ::: "memory");

        Hp += DH;
    }
}

// ---------------- Pass 3: O = H(65536x512) @ wO(512x128) ----------------
__global__ __launch_bounds__(256, 1) void k_O(const float* __restrict__ H,
                                              const float* __restrict__ wO,
                                              float* __restrict__ O) {
    __shared__ __align__(16) f16 Bt[DOUT][520];
    __shared__ __align__(16) f16 At[64][136];
    const int tid = threadIdx.x;
    const int wv = tid >> 6, ln = tid & 63, l15 = ln & 15, g = ln >> 4;
    const int m0 = (int)blockIdx.x * 64;

    // stage B (transpose to [n][k]) in 4x4 register blocks (b64 writes)
    #pragma unroll
    for (int u = 0; u < 16; ++u) {
        const int uid = u * 256 + tid;     // 0..4095
        const int c4 = (uid & 31) << 2;    // n base 0..124
        const int r4 = (uid >> 5) << 2;    // k base 0..508
        float4 w[4];
        #pragma unroll
        for (int j = 0; j < 4; ++j)
            w[j] = *(const float4*)(wO + (size_t)(r4 + j) * DOUT + c4);
        #pragma unroll
        for (int n = 0; n < 4; ++n) {
            f16x4 v;
            #pragma unroll
            for (int j = 0; j < 4; ++j) v[j] = (f16)((&w[j].x)[n]);
            *(f16x4*)(&Bt[c4 + n][r4]) = v;
        }
    }

    f32x4 acc[8];
    #pragma unroll
    for (int nt = 0; nt < 8; ++nt) acc[nt] = (f32x4){0.f, 0.f, 0.f, 0.f};

    for (int kc = 0; kc < 4; ++kc) {
        __syncthreads();
        {
            int r = tid >> 2;
            int cb = (tid & 3) << 5;
            #pragma unroll
            for (int u = 0; u < 8; ++u) {
                int c = cb + u * 4;
                const float4 x4 = *(const float4*)(H + (size_t)(m0 + r) * DH + kc * 128 + c);
                f16x4 h4;
                h4[0] = (f16)x4.x; h4[1] = (f16)x4.y; h4[2] = (f16)x4.z; h4[3] = (f16)x4.w;
                *(f16x4*)((char*)&At[r][0] + c * 2) = h4;
            }
        }
        __syncthreads();
        #pragma unroll
        for (int c = 0; c < 8; ++c) {
            const int k0 = c * 16 + g * 4;
            const f16x4 a = *(const f16x4*)((const char*)&At[wv * 16 + l15][0] + k0 * 2);
            #pragma unroll
            for (int nt = 0; nt < 8; ++nt) {
                const f16x4 b =
                    *(const f16x4*)((const char*)&Bt[nt * 16 + l15][0] + (kc * 128 + k0) * 2);
                acc[nt] = MFMA16(a, b, acc[nt]);
            }
        }
    }
    #pragma unroll
    for (int i = 0; i < 4; ++i) {
        const int m = m0 + wv * 16 + g * 4 + i;
        #pragma unroll
        for (int nt = 0; nt < 8; ++nt) O[(size_t)m * DOUT + nt * 16 + l15] = acc[nt][i];
    }
}

extern "C" void kernel_launch(void* const* d_in, const int* in_sizes, int n_in,
                              void* d_out, int out_size, void* d_ws, size_t ws_size,
                              hipStream_t stream) {
    const float* X  = (const float*)d_in[0];
    const float* h0 = (const float*)d_in[1];
    const float* wI = (const float*)d_in[2];
    const float* wR = (const float*)d_in[3];
    const float* wO = (const float*)d_in[4];
    float* O = (float*)d_out;
    float* H = O + O_ELEMS;  // H region; also holds xI (fp32) before in-place scan

    k_xI<<<1024, 256, 0, stream>>>(X, wI, H);   // xI -> H region
    k_scan<<<4, 512, 0, stream>>>(wR, h0, H);   // in-place: xI -> H
    k_O<<<1024, 256, 0, stream>>>(H, wO, O);    // O = H @ wO
}